// Round 1
// baseline (46.574 us; speedup 1.0000x reference)
//
#include <hip/hip_runtime.h>
#include <math.h>

// Problem constants (fixed shapes from reference)
#define BATCH   8
#define HGRID   64
#define WGRID   64
#define DDIM    256
#define NPTS    1024
#define ROWS    65          // HGRID + 1 (NaN pad row 0)
#define COLS    65
#define KWIN    15          // (2*R_WIN+1)*(2*C_WIN+1) = 3*5
#define BN      (BATCH*NPTS)

// ---------------------------------------------------------------------------
// Kernel 1: proj[m,d] = sum_c c_t[m,c] * W_a[c,d]   (m = b*N+n)
// fp32 tiled GEMM, 64x64 tile, K-tile 64, 256 threads, 4x4 micro-tile/thread.
// ---------------------------------------------------------------------------
__global__ __launch_bounds__(256) void proj_gemm(const float* __restrict__ C,
                                                 const float* __restrict__ Wa,
                                                 float* __restrict__ P) {
    __shared__ float As[64][68];   // +4 pad: keeps float4 alignment, kills conflicts
    __shared__ float Bs[64][68];
    const int t  = threadIdx.x;
    const int m0 = blockIdx.x * 64;
    const int n0 = blockIdx.y * 64;
    const int tx = t & 15;
    const int ty = t >> 4;
    float acc[4][4] = {};
    for (int kt = 0; kt < DDIM; kt += 64) {
        #pragma unroll
        for (int rep = 0; rep < 4; ++rep) {
            int f   = rep * 256 + t;     // float4 slot 0..1023
            int row = f >> 4;            // 16 float4 per 64-float row
            int c4  = (f & 15) * 4;
            *reinterpret_cast<float4*>(&As[row][c4]) =
                *reinterpret_cast<const float4*>(&C[(m0 + row) * DDIM + kt + c4]);
            *reinterpret_cast<float4*>(&Bs[row][c4]) =
                *reinterpret_cast<const float4*>(&Wa[(kt + row) * DDIM + n0 + c4]);
        }
        __syncthreads();
        #pragma unroll
        for (int k = 0; k < 64; ++k) {
            float a[4], b[4];
            #pragma unroll
            for (int i = 0; i < 4; ++i) a[i] = As[ty * 4 + i][k];
            #pragma unroll
            for (int j = 0; j < 4; ++j) b[j] = Bs[k][tx * 4 + j];
            #pragma unroll
            for (int i = 0; i < 4; ++i)
                #pragma unroll
                for (int j = 0; j < 4; ++j)
                    acc[i][j] += a[i] * b[j];
        }
        __syncthreads();
    }
    #pragma unroll
    for (int i = 0; i < 4; ++i) {
        float4 v = make_float4(acc[i][0], acc[i][1], acc[i][2], acc[i][3]);
        *reinterpret_cast<float4*>(&P[(m0 + ty * 4 + i) * DDIM + n0 + tx * 4]) = v;
    }
}

// ---------------------------------------------------------------------------
// Kernel 2: one wave (64 lanes) per (b,n) point. Lane owns d = lane*4..+3.
// Gather 15 window q-rows (float4), dot vs proj via wave shfl-reduce,
// softmax (+Gaussian window weights), weighted sum, float4 store.
// ---------------------------------------------------------------------------
__global__ __launch_bounds__(256) void local_attn(const float* __restrict__ q,
                                                  const float* __restrict__ p_t,
                                                  const float* __restrict__ proj,
                                                  float* __restrict__ out) {
    const int wave = threadIdx.x >> 6;
    const int lane = threadIdx.x & 63;
    const int pid  = blockIdx.x * 4 + wave;      // 0..8191
    const int b    = pid >> 10;                  // / NPTS
    const float p0f = p_t[pid * 2 + 0];
    const float p1f = p_t[pid * 2 + 1];
    const int p0 = (int)p0f;                     // truncation == floor (nonneg)
    const int p1 = (int)p1f;

    const float4 pr = *reinterpret_cast<const float4*>(&proj[pid * DDIM + lane * 4]);

    float qg[KWIN][4];
    float score[KWIN];
    float expw[KWIN];

    #pragma unroll
    for (int i = 0; i < 3; ++i) {
        // r = clip(p0 + i, 0, 65) % 65
        int rr = p0 + i;
        rr = rr < 0 ? 0 : (rr > ROWS ? ROWS : rr);
        rr = (rr == ROWS) ? 0 : rr;
        const float rf = (float)(rr - 1 > 0 ? rr - 1 : 0);
        const float dr = rf - p0f;                     // / R_WIN (=1)
        const float re = expf(-2.0f * dr * dr);
        #pragma unroll
        for (int j = 0; j < 5; ++j) {
            // c = clip(p1 + j - 1, 0, 65) % 65
            int cc = p1 + j - 1;
            cc = cc < 0 ? 0 : (cc > COLS ? COLS : cc);
            cc = (cc == COLS) ? 0 : cc;
            const float cf = (float)(cc - 1 > 0 ? cc - 1 : 0);
            const float dc = (cf - p1f) * 0.5f;        // / C_WIN (=2)
            const float ce = expf(-2.0f * dc * dc);
            const int k = i * 5 + j;
            expw[k] = re * ce;
            const bool valid = (rr != 0) && (cc != 0);  // wave-uniform
            float s;
            if (valid) {
                const float4 v = *reinterpret_cast<const float4*>(
                    &q[((size_t)((b * HGRID + rr - 1) * WGRID + cc - 1)) * DDIM + lane * 4]);
                qg[k][0] = v.x; qg[k][1] = v.y; qg[k][2] = v.z; qg[k][3] = v.w;
                s = v.x * pr.x + v.y * pr.y + v.z * pr.z + v.w * pr.w;
            } else {
                qg[k][0] = 0.f; qg[k][1] = 0.f; qg[k][2] = 0.f; qg[k][3] = 0.f;
                s = 0.f;
            }
            // wave-64 butterfly sum
            #pragma unroll
            for (int off = 32; off; off >>= 1) s += __shfl_xor(s, off, 64);
            score[k] = valid ? s : -INFINITY;
        }
    }

    // softmax over K=15 (replicated identically across lanes)
    float mx = score[0];
    #pragma unroll
    for (int k = 1; k < KWIN; ++k) mx = fmaxf(mx, score[k]);
    float sum = 0.f;
    float w[KWIN];
    #pragma unroll
    for (int k = 0; k < KWIN; ++k) { w[k] = expf(score[k] - mx); sum += w[k]; }
    const float inv = 1.0f / sum;

    float4 o = make_float4(0.f, 0.f, 0.f, 0.f);
    #pragma unroll
    for (int k = 0; k < KWIN; ++k) {
        const float wk = w[k] * inv * expw[k];
        o.x += wk * qg[k][0];
        o.y += wk * qg[k][1];
        o.z += wk * qg[k][2];
        o.w += wk * qg[k][3];
    }
    *reinterpret_cast<float4*>(&out[pid * DDIM + lane * 4]) = o;
}

// ---------------------------------------------------------------------------
extern "C" void kernel_launch(void* const* d_in, const int* in_sizes, int n_in,
                              void* d_out, int out_size, void* d_ws, size_t ws_size,
                              hipStream_t stream) {
    const float* q   = (const float*)d_in[0];
    const float* c_t = (const float*)d_in[1];
    const float* p_t = (const float*)d_in[2];
    const float* W_a = (const float*)d_in[3];
    float* out  = (float*)d_out;
    float* proj = (float*)d_ws;                 // BN*DDIM*4 = 8 MB scratch

    dim3 gemm_grid(BN / 64, DDIM / 64);         // 128 x 4
    proj_gemm<<<gemm_grid, 256, 0, stream>>>(c_t, W_a, proj);

    local_attn<<<BN / 4, 256, 0, stream>>>(q, p_t, proj, out);
}